// Round 1
// baseline (1848.587 us; speedup 1.0000x reference)
//
#include <hip/hip_runtime.h>

#define DIM 512
#define N_ROWS 16384
#define K_CODES 8192
#define TM 128
#define TN 128
#define TKD 8
#define CG 8
#define CODES_PER_GROUP (K_CODES / CG)          // 1024
#define CHUNKS_PER_GROUP (CODES_PER_GROUP / TN) // 8
#define OUT_ELEMS (N_ROWS * DIM)                // 8388608

// ---------------- kernel 1: per-code squared norms ----------------
__global__ __launch_bounds__(256) void vq_enorm_kernel(const float* __restrict__ emb,
                                                       float* __restrict__ enorm) {
  int gid  = blockIdx.x * 256 + threadIdx.x;
  int code = gid >> 6;          // one wave per code
  int lane = gid & 63;
  const float4* p = (const float4*)(emb + code * DIM + lane * 8);
  float4 a = p[0], b = p[1];
  float s = a.x*a.x + a.y*a.y + a.z*a.z + a.w*a.w
          + b.x*b.x + b.y*b.y + b.z*b.z + b.w*b.w;
  #pragma unroll
  for (int off = 32; off > 0; off >>= 1) s += __shfl_down(s, off);
  if (lane == 0) enorm[code] = s;
}

// ---------------- kernel 2: fused GEMM + running argmin ----------------
// dist(r,n) = ||e_n||^2 - 2 * x_r . e_n   (|x_r|^2 is constant per row)
__global__ __launch_bounds__(256) void vq_argmin_kernel(
    const float* __restrict__ x, const float* __restrict__ emb,
    const float* __restrict__ enorm,
    float* __restrict__ cand_d, int* __restrict__ cand_i) {
  __shared__ float As[TKD][TM];   // 4 KB
  __shared__ float Bs[TKD][TN];   // 4 KB
  __shared__ float red_d[16][TM]; // 8 KB
  __shared__ int   red_i[16][TM]; // 8 KB

  const int row0 = blockIdx.x * TM;
  const int cg   = blockIdx.y;
  const int tid  = threadIdx.x;
  const int tx   = tid & 15;      // code-group within tile
  const int ty   = tid >> 4;      // row-group within tile

  float best_d[8];
  int   best_i[8];
  #pragma unroll
  for (int i = 0; i < 8; ++i) { best_d[i] = 3.4e38f; best_i[i] = 0; }

  // staging-load assignment: 256 threads cover 128 rows x 8 cols as float4
  const int lr = tid >> 1;           // 0..127
  const int lc = (tid & 1) * 4;      // 0 or 4
  const float* xrow = x + (row0 + lr) * DIM + lc;

  for (int chunk = 0; chunk < CHUNKS_PER_GROUP; ++chunk) {
    const int col0 = cg * CODES_PER_GROUP + chunk * TN;
    const float* erow = emb + (col0 + lr) * DIM + lc;

    float acc[8][8];
    #pragma unroll
    for (int i = 0; i < 8; ++i)
      #pragma unroll
      for (int j = 0; j < 8; ++j) acc[i][j] = 0.0f;

    for (int d0 = 0; d0 < DIM; d0 += TKD) {
      __syncthreads();
      float4 va = *(const float4*)(xrow + d0);
      float4 vb = *(const float4*)(erow + d0);
      As[lc + 0][lr] = va.x; As[lc + 1][lr] = va.y;
      As[lc + 2][lr] = va.z; As[lc + 3][lr] = va.w;
      Bs[lc + 0][lr] = vb.x; Bs[lc + 1][lr] = vb.y;
      Bs[lc + 2][lr] = vb.z; Bs[lc + 3][lr] = vb.w;
      __syncthreads();
      #pragma unroll
      for (int k = 0; k < TKD; ++k) {
        float4 a0 = *(const float4*)&As[k][ty * 8];
        float4 a1 = *(const float4*)&As[k][ty * 8 + 4];
        float4 b0 = *(const float4*)&Bs[k][tx * 8];
        float4 b1 = *(const float4*)&Bs[k][tx * 8 + 4];
        float a[8] = {a0.x, a0.y, a0.z, a0.w, a1.x, a1.y, a1.z, a1.w};
        float b[8] = {b0.x, b0.y, b0.z, b0.w, b1.x, b1.y, b1.z, b1.w};
        #pragma unroll
        for (int i = 0; i < 8; ++i)
          #pragma unroll
          for (int j = 0; j < 8; ++j)
            acc[i][j] = fmaf(a[i], b[j], acc[i][j]);
      }
    }

    // chunk epilogue: distances + running min (ascending j keeps lowest idx on ties)
    float4 e0 = *(const float4*)&enorm[col0 + tx * 8];
    float4 e1 = *(const float4*)&enorm[col0 + tx * 8 + 4];
    float en[8] = {e0.x, e0.y, e0.z, e0.w, e1.x, e1.y, e1.z, e1.w};
    #pragma unroll
    for (int i = 0; i < 8; ++i) {
      #pragma unroll
      for (int j = 0; j < 8; ++j) {
        float dist = en[j] - 2.0f * acc[i][j];
        if (dist < best_d[i]) { best_d[i] = dist; best_i[i] = col0 + tx * 8 + j; }
      }
    }
  }

  // cross-thread reduction: 16 tx-threads share each row
  __syncthreads();
  #pragma unroll
  for (int i = 0; i < 8; ++i) {
    red_d[tx][ty * 8 + i] = best_d[i];
    red_i[tx][ty * 8 + i] = best_i[i];
  }
  __syncthreads();
  if (tid < TM) {
    float bd = red_d[0][tid];
    int   bi = red_i[0][tid];
    #pragma unroll
    for (int t = 1; t < 16; ++t) {
      float d = red_d[t][tid];
      int   ix = red_i[t][tid];
      if (d < bd || (d == bd && ix < bi)) { bd = d; bi = ix; }
    }
    cand_d[cg * N_ROWS + row0 + tid] = bd;
    cand_i[cg * N_ROWS + row0 + tid] = bi;
  }
}

// ---------------- kernel 3: merge per-group candidates ----------------
__global__ __launch_bounds__(256) void vq_merge_kernel(const float* __restrict__ cand_d,
                                                       const int* __restrict__ cand_i,
                                                       int* __restrict__ idx,
                                                       float* __restrict__ loss_slot) {
  int r = blockIdx.x * 256 + threadIdx.x;
  if (r == 0) *loss_slot = 0.0f;   // zero the loss accumulator before gather
  if (r >= N_ROWS) return;
  float bd = cand_d[r];
  int   bi = cand_i[r];
  #pragma unroll
  for (int g = 1; g < CG; ++g) {
    float d  = cand_d[g * N_ROWS + r];
    int   ix = cand_i[g * N_ROWS + r];
    if (d < bd || (d == bd && ix < bi)) { bd = d; bi = ix; }
  }
  idx[r] = bi;
}

// ---------------- kernel 4: gather + outputs + loss ----------------
__global__ __launch_bounds__(256) void vq_gather_kernel(
    const float* __restrict__ x, const float* __restrict__ emb,
    const int* __restrict__ idx,
    float* __restrict__ out, float* __restrict__ quant,
    float* __restrict__ loss_slot) {
  __shared__ float wsum[4];
  const int wave = threadIdx.x >> 6;
  const int lane = threadIdx.x & 63;
  const int row  = blockIdx.x * 4 + wave;
  const int code = idx[row];
  const float4* xp = (const float4*)(x   + row  * DIM + lane * 8);
  const float4* ep = (const float4*)(emb + code * DIM + lane * 8);
  float s = 0.0f;
  #pragma unroll
  for (int t = 0; t < 2; ++t) {
    float4 xv = xp[t];
    float4 ev = ep[t];
    float dx = ev.x - xv.x, dy = ev.y - xv.y, dz = ev.z - xv.z, dw = ev.w - xv.w;
    s += dx * dx + dy * dy + dz * dz + dw * dw;
    float4 ov = make_float4(xv.x + dx, xv.y + dy, xv.z + dz, xv.w + dw);
    ((float4*)(out   + row * DIM + lane * 8))[t] = ov;
    ((float4*)(quant + row * DIM + lane * 8))[t] = ev;
  }
  #pragma unroll
  for (int off = 32; off > 0; off >>= 1) s += __shfl_down(s, off);
  if (lane == 0) wsum[wave] = s;
  __syncthreads();
  if (threadIdx.x == 0) {
    float tot = wsum[0] + wsum[1] + wsum[2] + wsum[3];
    atomicAdd(loss_slot, tot * (1.25f / (float)OUT_ELEMS));
  }
}

extern "C" void kernel_launch(void* const* d_in, const int* in_sizes, int n_in,
                              void* d_out, int out_size, void* d_ws, size_t ws_size,
                              hipStream_t stream) {
  const float* x   = (const float*)d_in[0];   // [16384, 512]
  const float* emb = (const float*)d_in[1];   // [8192, 512]
  float* out   = (float*)d_out;               // 8388608
  float* quant = out + OUT_ELEMS;             // 8388608
  float* loss  = out + 2 * OUT_ELEMS;         // 1

  char*  ws     = (char*)d_ws;
  float* enorm  = (float*)ws;                                   // 32 KB
  float* cand_d = (float*)(ws + 64 * 1024);                     // CG*16384*4 = 512 KB
  int*   cand_i = (int*)  (ws + 64 * 1024 + CG * N_ROWS * 4);   // 512 KB
  int*   idx    = (int*)  (ws + 64 * 1024 + 2 * CG * N_ROWS * 4); // 64 KB

  vq_enorm_kernel<<<K_CODES * 64 / 256, 256, 0, stream>>>(emb, enorm);
  vq_argmin_kernel<<<dim3(N_ROWS / TM, CG), 256, 0, stream>>>(x, emb, enorm, cand_d, cand_i);
  vq_merge_kernel<<<N_ROWS / 256, 256, 0, stream>>>(cand_d, cand_i, idx, loss);
  vq_gather_kernel<<<N_ROWS / 4, 256, 0, stream>>>(x, emb, idx, out, quant, loss);
}